// Round 9
// baseline (144.337 us; speedup 1.0000x reference)
//
#include <hip/hip_runtime.h>
#include <hip/hip_bf16.h>
#include <math.h>

typedef __attribute__((ext_vector_type(8))) short bf16x8;
typedef __attribute__((ext_vector_type(4))) float f32x4;

#define MFMA16 __builtin_amdgcn_mfma_f32_16x16x32_bf16

static constexpr int TSEQ = 4096;
static constexpr int EMB = 1024;
static constexpr int HD = 64;

__device__ __forceinline__ unsigned short f2bf(float f) {
    unsigned u = __builtin_bit_cast(unsigned, f);
    u += 0x7fffu + ((u >> 16) & 1u);
    return (unsigned short)(u >> 16);
}

__device__ __forceinline__ void gll16(const void* g, void* l) {
    __builtin_amdgcn_global_load_lds(
        (const __attribute__((address_space(1))) void*)g,
        (__attribute__((address_space(3))) void*)l, 16, 0, 0);
}

#define WAITV6 asm volatile("s_waitcnt vmcnt(6)" ::: "memory")
#define WAITV0 asm volatile("s_waitcnt vmcnt(0)" ::: "memory")
#define WAITLG asm volatile("s_waitcnt lgkmcnt(0)" ::: "memory")
__device__ __forceinline__ void barrier_sync() {
    asm volatile("" ::: "memory");
    __builtin_amdgcn_s_barrier();
    asm volatile("" ::: "memory");
}

// Pack W -> Wp, LANE-LINEAR frag tiles: tile (kc=k>>5, nt=n>>4) of 1KB; within
// the tile, lane l = (quad=k-octet, col=n&15) owns bytes l*16..+16, i.e.
// ushort idx = ((k>>3)&3)*128 + (n&15)*8 + (k&7). Conflict-free ds_read_b128.
// Wq pre-scaled 1/32.
__global__ void prep_w(const float* __restrict__ Wq, const float* __restrict__ Wk,
                       const float* __restrict__ Wv, unsigned short* __restrict__ Wp) {
    int id = blockIdx.x * 256 + threadIdx.x;        // 0..196607
    int wsel = id >> 16;
    int t = id & 65535;                             // = k*64 + n0 (coalesced read)
    int k = t >> 6, n0 = t & 63;
    const float* W = (wsel == 0) ? Wq : (wsel == 1) ? Wk : Wv;
    float v = W[t];
    if (wsel == 0) v *= 0.03125f;                   // 1/sqrt(1024)
    int n = wsel * 64 + n0;
    Wp[(k >> 5) * 6144 + (n >> 4) * 512 + ((k >> 3) & 3) * 128 + (n & 15) * 8 + (k & 7)] = f2bf(v);
}

// Projection v9 (kept verbatim - best measured): grid 256 x 1024 thr, 16
// waves, minimal 160 MB traffic, T3/T4 counted-vmcnt triple-buffer schedule.
__global__ __launch_bounds__(1024, 4) void proj_kernel(const float* __restrict__ X,
        const unsigned short* __restrict__ Wp, unsigned short* __restrict__ Qp,
        unsigned short* __restrict__ Kp, unsigned short* __restrict__ Vp) {
    __shared__ unsigned short wlds[3][12288];       // 3 x 24 KB W slab-pair
    __shared__ unsigned short xlds[3][4096];        // 3 x 8 KB X slab (frag order)

    const int tid = threadIdx.x;
    const int lane = tid & 63, wave = tid >> 6;
    const int col = lane & 15, quad = lane >> 4;
    const int mq = wave >> 2, nw = wave & 3;
    const int row0 = blockIdx.x * 64;

    f32x4 acc[3];
#pragma unroll
    for (int j = 0; j < 3; j++) acc[j] = (f32x4)(0.0f);

    const char* wsrc = (const char*)Wp + lane * 16;
    auto stageW = [&](int p, int b) {
        char* d = (char*)wlds + b * 24576;
#pragma unroll
        for (int u = 0; u < 2; u++) {
            const char* s = wsrc + (size_t)(2 * p + u) * 12288;
            char* du = d + u * 12288;
            gll16(s + wave * 1024,       du + wave * 1024);
            gll16(s + (4 + wave) * 1024, du + (4 + wave) * 1024);
            gll16(s + (8 + wave) * 1024, du + (8 + wave) * 1024);
        }
    };
    const int u2 = tid - 256;                        // 0..511 for waves 4-11
    const int xrow = u2 >> 3, q8 = u2 & 7;
    const bool xstager = (wave >= 4) && (wave < 12);
    const float* xsrc = xstager ? (X + (size_t)(row0 + xrow) * EMB + q8 * 8) : X;
    const int xo = (q8 >> 2) * 4096 + (xrow >> 4) * 1024 + (q8 & 3) * 256 + (xrow & 15) * 16;

    auto wr8 = [&](int b, float4 f0, float4 f1) {
        union { unsigned short s[8]; bf16x8 v; } r;
        r.s[0] = f2bf(f0.x); r.s[1] = f2bf(f0.y); r.s[2] = f2bf(f0.z); r.s[3] = f2bf(f0.w);
        r.s[4] = f2bf(f1.x); r.s[5] = f2bf(f1.y); r.s[6] = f2bf(f1.z); r.s[7] = f2bf(f1.w);
        *(bf16x8*)((char*)xlds + b * 8192 + xo) = r.v;
    };
    auto compute = [&](int b) {
        bf16x8 A[2], Wf[2][3];
        const char* xb = (const char*)xlds + b * 8192;
        const char* wb = (const char*)wlds + b * 24576;
#pragma unroll
        for (int u = 0; u < 2; u++) {
            A[u] = *(const bf16x8*)(xb + u * 4096 + mq * 1024 + lane * 16);
#pragma unroll
            for (int j = 0; j < 3; j++)
                Wf[u][j] = *(const bf16x8*)(wb + u * 12288 + (j * 4 + nw) * 1024 + lane * 16);
        }
#pragma unroll
        for (int u = 0; u < 2; u++)
#pragma unroll
            for (int j = 0; j < 3; j++)
                acc[j] = MFMA16(A[u], Wf[u][j], acc[j], 0, 0, 0);
    };

    int bc = 0, bx = 1, bw = 2;                      // consume / x-write / w-stage
    float4 pa0, pa1, qa0, qa1;

    if (wave < 4) {
        stageW(0, 0);
        stageW(1, 1);
        WAITV6;
    } else if (xstager) {
        float4 t0 = *(const float4*)(xsrc);
        float4 t1 = *(const float4*)(xsrc + 4);
        wr8(0, t0, t1);
        pa0 = *(const float4*)(xsrc + 64);
        pa1 = *(const float4*)(xsrc + 68);
        WAITLG;
    }
    barrier_sync();

    auto step = [&](int s, float4& w0, float4& w1, float4& l0, float4& l1) {
        if (wave < 4) {
            if (s + 2 < 16) stageW(s + 2, bw);
        } else if (xstager) {
            if (s + 2 < 16) {
                l0 = *(const float4*)(xsrc + (s + 2) * 64);
                l1 = *(const float4*)(xsrc + (s + 2) * 64 + 4);
            }
            if (s + 1 < 16) wr8(bx, w0, w1);
        }
        compute(bc);
        if (wave < 4) {
            if (s + 2 < 16) { WAITV6; } else { WAITV0; }
        } else if (xstager) {
            WAITLG;
        }
        barrier_sync();
        int t = bc; bc = bx; bx = bw; bw = t;        // rotate buffers
    };

    for (int si = 0; si < 8; si++) {
        step(2 * si,     pa0, pa1, qa0, qa1);
        step(2 * si + 1, qa0, qa1, pa0, pa1);
    }

    const int t = blockIdx.x * 4 + mq;
#pragma unroll
    for (int r = 0; r < 4; r++)
        Qp[t * 1024 + (nw >> 1) * 512 + (quad * 4 + r) * 32 +
           ((nw & 1) * 2 + (col >> 3)) * 8 + (col & 7)] = f2bf(acc[0][r]);
#pragma unroll
    for (int r = 0; r < 4; r++)
        Kp[(t * 2 + (nw >> 1)) * 512 + (quad * 4 + r) * 32 +
           ((nw & 1) * 2 + (col >> 3)) * 8 + (col & 7)] = f2bf(acc[1][r]);
    {
        ushort4 pk;
        pk.x = f2bf(acc[2][0]); pk.y = f2bf(acc[2][1]);
        pk.z = f2bf(acc[2][2]); pk.w = f2bf(acc[2][3]);
        *(ushort4*)&Vp[(t >> 1) * 2048 + nw * 512 + col * 32 + (t & 1) * 16 + quad * 4] = pk;
    }
}

// Flash attention v2: 256 blocks (batch, 64-row q-block) x 512 threads
// (8 waves). QBLK=64 halves KV L2 traffic (264 -> 132 MB) at unchanged MFMA
// count: each wave processes chunks c = wave (mod 8) for FOUR 16-row tiles.
// Causality: c < 2tb full; c == 2tb diag (mask formula no-ops for m>=2);
// c == 2tb+1 skips m<2 (wave-uniform). Per-row chunk sets, exp inputs and
// merge order identical to v9's attn -> bitwise-equal output. plds/cmb share
// one 80 KB pool (disjoint phases); final divide+store split across waves 0/1.
__global__ __launch_bounds__(512, 2) void attn_kernel(const unsigned short* __restrict__ Qp,
        const unsigned short* __restrict__ Kp, const unsigned short* __restrict__ Vp,
        float* __restrict__ Out) {
    __shared__ __align__(16) char pool[81920];     // 80 KB
    auto cmb  = (float (*)[4][64][20])pool;        // [slot][m][lane][20]
    auto plds = (unsigned short (*)[4][640])pool;  // [wave][m][640]

    const int lane = threadIdx.x & 63, wave = threadIdx.x >> 6;
    const int col = lane & 15, quad = lane >> 4;
    const int batch = blockIdx.x & 3;
    const int tb = blockIdx.x >> 2;                // 0..63
    const int q0 = tb * 64;
    const int tb2 = tb * 2;
    const int cmax = tb2 + 1;
    const size_t bT = (size_t)batch * TSEQ;
    const int fragoff = col * 64 + quad * 16;

    const char* QpB = (const char*)Qp;
    const char* KpB = (const char*)Kp;
    const char* VpB = (const char*)Vp;
    const int gt = (int)((bT + q0) >> 4);
    const int c0 = (int)(bT >> 5);

    bf16x8 aq[4][2];
#pragma unroll
    for (int m = 0; m < 4; m++)
#pragma unroll
        for (int h = 0; h < 2; h++)
            aq[m][h] = *(const bf16x8*)(QpB + (size_t)((gt + m) * 2 + h) * 1024 + fragoff);

    f32x4 o[4][4];
    f32x4 lsum[4];
#pragma unroll
    for (int m = 0; m < 4; m++) {
        lsum[m] = (f32x4)(0.0f);
#pragma unroll
        for (int t = 0; t < 4; t++) o[m][t] = (f32x4)(0.0f);
    }

    for (int c = wave; c <= cmax; c += 8) {
        const char* kb = KpB + (size_t)(c0 + c) * 4096;
        const char* vb = VpB + (size_t)(c0 + c) * 4096;
        bf16x8 bk[2][2], bv[4];
#pragma unroll
        for (int j = 0; j < 2; j++)
#pragma unroll
            for (int h = 0; h < 2; h++)
                bk[j][h] = *(const bf16x8*)(kb + j * 2048 + h * 1024 + fragoff);
#pragma unroll
        for (int t = 0; t < 4; t++)
            bv[t] = *(const bf16x8*)(vb + t * 1024 + fragoff);

        const int crel = c - tb2;                  // <0 full; 0 diag m01; 1 diag m23
        const bool skipm01 = (crel >= 1);
        const bool haveMask = (crel >= 0);

        f32x4 s[4][2];
#pragma unroll
        for (int m = 0; m < 4; m++) {
            if (skipm01 && m < 2) continue;        // wave-uniform
#pragma unroll
            for (int j = 0; j < 2; j++) {
                f32x4 a = MFMA16(aq[m][0], bk[j][0], (f32x4)(0.0f), 0, 0, 0);
                s[m][j] = MFMA16(aq[m][1], bk[j][1], a, 0, 0, 0);
            }
        }
#pragma unroll
        for (int m = 0; m < 4; m++) {
            if (skipm01 && m < 2) continue;
#pragma unroll
            for (int j = 0; j < 2; j++)
#pragma unroll
                for (int r = 0; r < 4; r++) {
                    float v = s[m][j][r];
                    if (haveMask && (crel * 32 + j * 16 + col > m * 16 + quad * 4 + r))
                        v = -INFINITY;
                    const float p = __expf(v);     // |score| small: safe without max-sub
                    lsum[m][r] += p;
                    plds[wave][m][(quad * 4 + r) * 40 + j * 16 + col] =
                        (unsigned short)(__builtin_bit_cast(unsigned, p) >> 16);
                }
        }
#pragma unroll
        for (int m = 0; m < 4; m++) {
            if (skipm01 && m < 2) continue;
            bf16x8 pa = *(const bf16x8*)(&plds[wave][m][col * 40 + quad * 8]);
#pragma unroll
            for (int t = 0; t < 4; t++)
                o[m][t] = MFMA16(pa, bv[t], o[m][t], 0, 0, 0);
        }
    }

    // staged tree reduction: 8 -> 4 -> 2 -> exchange between waves 0/1
    auto wr1 = [&](int s, int m) {
#pragma unroll
        for (int t = 0; t < 4; t++)
            *(f32x4*)&cmb[s][m][lane][t * 4] = o[m][t];
        *(f32x4*)&cmb[s][m][lane][16] = lsum[m];
    };
    auto rd1 = [&](int s, int m) {
#pragma unroll
        for (int t = 0; t < 4; t++)
            o[m][t] += *(const f32x4*)&cmb[s][m][lane][t * 4];
        lsum[m] += *(const f32x4*)&cmb[s][m][lane][16];
    };
    auto wr = [&](int s) {
#pragma unroll
        for (int m = 0; m < 4; m++) wr1(s, m);
    };
    auto rd = [&](int s) {
#pragma unroll
        for (int m = 0; m < 4; m++) rd1(s, m);
    };
    auto finalize = [&](int m) {
#pragma unroll
        for (int off = 1; off < 16; off <<= 1)
#pragma unroll
            for (int r = 0; r < 4; r++)
                lsum[m][r] += __shfl_xor(lsum[m][r], off, 64);
#pragma unroll
        for (int r = 0; r < 4; r++) {
            const float inv = 1.0f / lsum[m][r];
            const size_t orow = (bT + q0 + m * 16 + quad * 4 + r) * HD;
#pragma unroll
            for (int t = 0; t < 4; t++)
                Out[orow + t * 16 + col] = o[m][t][r] * inv;
        }
    };

    __syncthreads();                               // all plds reads done (pool reuse)
    if (wave >= 4) wr(wave - 4);
    __syncthreads();
    if (wave < 4) rd(wave);
    __syncthreads();
    if (wave == 2 || wave == 3) wr(wave);
    __syncthreads();
    if (wave < 2) rd(wave + 2);
    __syncthreads();
    // waves 0/1 hold complementary halves; exchange and split the epilogue
    if (wave == 1) { wr1(0, 0); wr1(0, 1); }
    if (wave == 0) { wr1(1, 2); wr1(1, 3); }
    __syncthreads();
    if (wave == 0) {
        rd1(0, 0); rd1(0, 1);
        finalize(0); finalize(1);
    } else if (wave == 1) {
        rd1(1, 2); rd1(1, 3);
        finalize(2); finalize(3);
    }
}

extern "C" void kernel_launch(void* const* d_in, const int* in_sizes, int n_in,
                              void* d_out, int out_size, void* d_ws, size_t ws_size,
                              hipStream_t stream) {
    const float* x  = (const float*)d_in[0];
    const float* Wq = (const float*)d_in[1];
    const float* Wk = (const float*)d_in[2];
    const float* Wv = (const float*)d_in[3];
    float* out = (float*)d_out;

    char* w = (char*)d_ws;
    unsigned short* Wp = (unsigned short*)(w);                            // 384 KB
    unsigned short* Qp = (unsigned short*)(w + (512 << 10));              // 2 MB
    unsigned short* Kp = (unsigned short*)(w + (512 << 10) + (2 << 20));  // 2 MB
    unsigned short* Vp = (unsigned short*)(w + (512 << 10) + (4 << 20));  // 2 MB

    hipLaunchKernelGGL(prep_w, dim3(768), dim3(256), 0, stream, Wq, Wk, Wv, Wp);
    hipLaunchKernelGGL(proj_kernel, dim3(256), dim3(1024), 0, stream, x, Wp, Qp, Kp, Vp);
    hipLaunchKernelGGL(attn_kernel, dim3(256), dim3(512), 0, stream, Qp, Kp, Vp, out);
}

// Round 10
// 139.013 us; speedup vs baseline: 1.0383x; 1.0383x over previous
//
#include <hip/hip_runtime.h>
#include <hip/hip_bf16.h>
#include <math.h>

typedef __attribute__((ext_vector_type(8))) short bf16x8;
typedef __attribute__((ext_vector_type(4))) float f32x4;

#define MFMA16 __builtin_amdgcn_mfma_f32_16x16x32_bf16

static constexpr int TSEQ = 4096;
static constexpr int EMB = 1024;
static constexpr int HD = 64;

__device__ __forceinline__ unsigned short f2bf(float f) {
    unsigned u = __builtin_bit_cast(unsigned, f);
    u += 0x7fffu + ((u >> 16) & 1u);
    return (unsigned short)(u >> 16);
}

__device__ __forceinline__ void gll16(const void* g, void* l) {
    __builtin_amdgcn_global_load_lds(
        (const __attribute__((address_space(1))) void*)g,
        (__attribute__((address_space(3))) void*)l, 16, 0, 0);
}

#define WAITV6 asm volatile("s_waitcnt vmcnt(6)" ::: "memory")
#define WAITV0 asm volatile("s_waitcnt vmcnt(0)" ::: "memory")
#define WAITLG asm volatile("s_waitcnt lgkmcnt(0)" ::: "memory")
__device__ __forceinline__ void barrier_sync() {
    asm volatile("" ::: "memory");
    __builtin_amdgcn_s_barrier();
    asm volatile("" ::: "memory");
}

// Pack W -> Wp, LANE-LINEAR frag tiles: tile (kc=k>>5, nt=n>>4) of 1KB; within
// the tile, lane l = (quad=k-octet, col=n&15) owns bytes l*16..+16, i.e.
// ushort idx = ((k>>3)&3)*128 + (n&15)*8 + (k&7). Conflict-free ds_read_b128.
// Wq pre-scaled 1/32.
__global__ void prep_w(const float* __restrict__ Wq, const float* __restrict__ Wk,
                       const float* __restrict__ Wv, unsigned short* __restrict__ Wp) {
    int id = blockIdx.x * 256 + threadIdx.x;        // 0..196607
    int wsel = id >> 16;
    int t = id & 65535;                             // = k*64 + n0 (coalesced read)
    int k = t >> 6, n0 = t & 63;
    const float* W = (wsel == 0) ? Wq : (wsel == 1) ? Wk : Wv;
    float v = W[t];
    if (wsel == 0) v *= 0.03125f;                   // 1/sqrt(1024)
    int n = wsel * 64 + n0;
    Wp[(k >> 5) * 6144 + (n >> 4) * 512 + ((k >> 3) & 3) * 128 + (n & 15) * 8 + (k & 7)] = f2bf(v);
}

// Projection v9 (kept verbatim - best measured): grid 256 x 1024 thr, 16
// waves, minimal 160 MB traffic, T3/T4 counted-vmcnt triple-buffer schedule.
__global__ __launch_bounds__(1024, 4) void proj_kernel(const float* __restrict__ X,
        const unsigned short* __restrict__ Wp, unsigned short* __restrict__ Qp,
        unsigned short* __restrict__ Kp, unsigned short* __restrict__ Vp) {
    __shared__ unsigned short wlds[3][12288];       // 3 x 24 KB W slab-pair
    __shared__ unsigned short xlds[3][4096];        // 3 x 8 KB X slab (frag order)

    const int tid = threadIdx.x;
    const int lane = tid & 63, wave = tid >> 6;
    const int col = lane & 15, quad = lane >> 4;
    const int mq = wave >> 2, nw = wave & 3;
    const int row0 = blockIdx.x * 64;

    f32x4 acc[3];
#pragma unroll
    for (int j = 0; j < 3; j++) acc[j] = (f32x4)(0.0f);

    const char* wsrc = (const char*)Wp + lane * 16;
    auto stageW = [&](int p, int b) {
        char* d = (char*)wlds + b * 24576;
#pragma unroll
        for (int u = 0; u < 2; u++) {
            const char* s = wsrc + (size_t)(2 * p + u) * 12288;
            char* du = d + u * 12288;
            gll16(s + wave * 1024,       du + wave * 1024);
            gll16(s + (4 + wave) * 1024, du + (4 + wave) * 1024);
            gll16(s + (8 + wave) * 1024, du + (8 + wave) * 1024);
        }
    };
    const int u2 = tid - 256;                        // 0..511 for waves 4-11
    const int xrow = u2 >> 3, q8 = u2 & 7;
    const bool xstager = (wave >= 4) && (wave < 12);
    const float* xsrc = xstager ? (X + (size_t)(row0 + xrow) * EMB + q8 * 8) : X;
    const int xo = (q8 >> 2) * 4096 + (xrow >> 4) * 1024 + (q8 & 3) * 256 + (xrow & 15) * 16;

    auto wr8 = [&](int b, float4 f0, float4 f1) {
        union { unsigned short s[8]; bf16x8 v; } r;
        r.s[0] = f2bf(f0.x); r.s[1] = f2bf(f0.y); r.s[2] = f2bf(f0.z); r.s[3] = f2bf(f0.w);
        r.s[4] = f2bf(f1.x); r.s[5] = f2bf(f1.y); r.s[6] = f2bf(f1.z); r.s[7] = f2bf(f1.w);
        *(bf16x8*)((char*)xlds + b * 8192 + xo) = r.v;
    };
    auto compute = [&](int b) {
        bf16x8 A[2], Wf[2][3];
        const char* xb = (const char*)xlds + b * 8192;
        const char* wb = (const char*)wlds + b * 24576;
#pragma unroll
        for (int u = 0; u < 2; u++) {
            A[u] = *(const bf16x8*)(xb + u * 4096 + mq * 1024 + lane * 16);
#pragma unroll
            for (int j = 0; j < 3; j++)
                Wf[u][j] = *(const bf16x8*)(wb + u * 12288 + (j * 4 + nw) * 1024 + lane * 16);
        }
#pragma unroll
        for (int u = 0; u < 2; u++)
#pragma unroll
            for (int j = 0; j < 3; j++)
                acc[j] = MFMA16(A[u], Wf[u][j], acc[j], 0, 0, 0);
    };

    int bc = 0, bx = 1, bw = 2;                      // consume / x-write / w-stage
    float4 pa0, pa1, qa0, qa1;

    if (wave < 4) {
        stageW(0, 0);
        stageW(1, 1);
        WAITV6;
    } else if (xstager) {
        float4 t0 = *(const float4*)(xsrc);
        float4 t1 = *(const float4*)(xsrc + 4);
        wr8(0, t0, t1);
        pa0 = *(const float4*)(xsrc + 64);
        pa1 = *(const float4*)(xsrc + 68);
        WAITLG;
    }
    barrier_sync();

    auto step = [&](int s, float4& w0, float4& w1, float4& l0, float4& l1) {
        if (wave < 4) {
            if (s + 2 < 16) stageW(s + 2, bw);
        } else if (xstager) {
            if (s + 2 < 16) {
                l0 = *(const float4*)(xsrc + (s + 2) * 64);
                l1 = *(const float4*)(xsrc + (s + 2) * 64 + 4);
            }
            if (s + 1 < 16) wr8(bx, w0, w1);
        }
        compute(bc);
        if (wave < 4) {
            if (s + 2 < 16) { WAITV6; } else { WAITV0; }
        } else if (xstager) {
            WAITLG;
        }
        barrier_sync();
        int t = bc; bc = bx; bx = bw; bw = t;        // rotate buffers
    };

    for (int si = 0; si < 8; si++) {
        step(2 * si,     pa0, pa1, qa0, qa1);
        step(2 * si + 1, qa0, qa1, pa0, pa1);
    }

    const int t = blockIdx.x * 4 + mq;
#pragma unroll
    for (int r = 0; r < 4; r++)
        Qp[t * 1024 + (nw >> 1) * 512 + (quad * 4 + r) * 32 +
           ((nw & 1) * 2 + (col >> 3)) * 8 + (col & 7)] = f2bf(acc[0][r]);
#pragma unroll
    for (int r = 0; r < 4; r++)
        Kp[(t * 2 + (nw >> 1)) * 512 + (quad * 4 + r) * 32 +
           ((nw & 1) * 2 + (col >> 3)) * 8 + (col & 7)] = f2bf(acc[1][r]);
    {
        ushort4 pk;
        pk.x = f2bf(acc[2][0]); pk.y = f2bf(acc[2][1]);
        pk.z = f2bf(acc[2][2]); pk.w = f2bf(acc[2][3]);
        *(ushort4*)&Vp[(t >> 1) * 2048 + nw * 512 + col * 32 + (t & 1) * 16 + quad * 4] = pk;
    }
}

// Flash attention (v9 structure restored): 512 blocks x 512 threads (8 waves),
// block = (batch, 32-row q-tile) heavy-first -> 2-resident/CU dynamic dispatch
// gives near-LPT load balance (v10's 256 static 1/CU blocks lost 2x to
// imbalance). Chunks split 8 ways; staged LDS tree reduction. Only change vs
// v9: the final exchange + shuffle-reduce + divide + store is SPLIT across
// waves 0 (m=0) and 1 (m=1) - addition stays commutative-only => bitwise
// identical output.
__global__ __launch_bounds__(512, 4) void attn_kernel(const unsigned short* __restrict__ Qp,
        const unsigned short* __restrict__ Kp, const unsigned short* __restrict__ Vp,
        float* __restrict__ Out) {
    __shared__ float cmb[4][2][64][20];            // 40 KB
    __shared__ unsigned short plds[8][2][640];     // 20 KB
    const int lane = threadIdx.x & 63, wave = threadIdx.x >> 6;
    const int col = lane & 15, quad = lane >> 4;
    const int batch = blockIdx.x & 3;
    const int ti = 127 - (blockIdx.x >> 2);
    const int q0 = ti * 32;
    const size_t bT = (size_t)batch * TSEQ;
    const int fragoff = col * 64 + quad * 16;

    const char* QpB = (const char*)Qp;
    const char* KpB = (const char*)Kp;
    const char* VpB = (const char*)Vp;
    const int gt = (int)((bT + q0) >> 4);
    const int c0 = (int)(bT >> 5);

    bf16x8 aq[2][2];
#pragma unroll
    for (int m = 0; m < 2; m++)
#pragma unroll
        for (int h = 0; h < 2; h++)
            aq[m][h] = *(const bf16x8*)(QpB + (size_t)((gt + m) * 2 + h) * 1024 + fragoff);

    f32x4 o[2][4];
    f32x4 lsum[2];
#pragma unroll
    for (int m = 0; m < 2; m++) {
        lsum[m] = (f32x4)(0.0f);
#pragma unroll
        for (int t = 0; t < 4; t++) o[m][t] = (f32x4)(0.0f);
    }

    for (int c = wave; c <= ti; c += 8) {
        const char* kb = KpB + (size_t)(c0 + c) * 4096;
        const char* vb = VpB + (size_t)(c0 + c) * 4096;
        bf16x8 bk[2][2], bv[4];
#pragma unroll
        for (int j = 0; j < 2; j++)
#pragma unroll
            for (int h = 0; h < 2; h++)
                bk[j][h] = *(const bf16x8*)(kb + j * 2048 + h * 1024 + fragoff);
#pragma unroll
        for (int t = 0; t < 4; t++)
            bv[t] = *(const bf16x8*)(vb + t * 1024 + fragoff);

        f32x4 s[2][2];
#pragma unroll
        for (int m = 0; m < 2; m++)
#pragma unroll
            for (int j = 0; j < 2; j++) {
                f32x4 a = MFMA16(aq[m][0], bk[j][0], (f32x4)(0.0f), 0, 0, 0);
                s[m][j] = MFMA16(aq[m][1], bk[j][1], a, 0, 0, 0);
            }
        const bool diag = (c == ti);
#pragma unroll
        for (int m = 0; m < 2; m++)
#pragma unroll
            for (int j = 0; j < 2; j++)
#pragma unroll
                for (int r = 0; r < 4; r++) {
                    float v = s[m][j][r];
                    if (diag && (j * 16 + col > m * 16 + quad * 4 + r)) v = -INFINITY;
                    const float p = __expf(v);   // |score| small: safe without max-sub
                    lsum[m][r] += p;
                    plds[wave][m][(quad * 4 + r) * 40 + j * 16 + col] =
                        (unsigned short)(__builtin_bit_cast(unsigned, p) >> 16);
                }
        bf16x8 pa[2];
#pragma unroll
        for (int m = 0; m < 2; m++)
            pa[m] = *(const bf16x8*)(&plds[wave][m][col * 40 + quad * 8]);
#pragma unroll
        for (int m = 0; m < 2; m++)
#pragma unroll
            for (int t = 0; t < 4; t++)
                o[m][t] = MFMA16(pa[m], bv[t], o[m][t], 0, 0, 0);
    }

    // staged tree reduction: 8 -> 4 -> 2, then waves 0/1 split the finish
    auto wr1 = [&](int s, int m) {
#pragma unroll
        for (int t = 0; t < 4; t++)
            *(f32x4*)&cmb[s][m][lane][t * 4] = o[m][t];
        *(f32x4*)&cmb[s][m][lane][16] = lsum[m];
    };
    auto rd1 = [&](int s, int m) {
#pragma unroll
        for (int t = 0; t < 4; t++)
            o[m][t] += *(const f32x4*)&cmb[s][m][lane][t * 4];
        lsum[m] += *(const f32x4*)&cmb[s][m][lane][16];
    };
    auto wr = [&](int s) { wr1(s, 0); wr1(s, 1); };
    auto rd = [&](int s) { rd1(s, 0); rd1(s, 1); };
    auto finalize = [&](int m) {
#pragma unroll
        for (int off = 1; off < 16; off <<= 1)
#pragma unroll
            for (int r = 0; r < 4; r++)
                lsum[m][r] += __shfl_xor(lsum[m][r], off, 64);
#pragma unroll
        for (int r = 0; r < 4; r++) {
            const float inv = 1.0f / lsum[m][r];
            const size_t orow = (bT + q0 + m * 16 + quad * 4 + r) * HD;
#pragma unroll
            for (int t = 0; t < 4; t++)
                Out[orow + t * 16 + col] = o[m][t][r] * inv;
        }
    };

    if (wave >= 4) wr(wave - 4);
    __syncthreads();
    if (wave < 4) rd(wave);
    __syncthreads();
    if (wave == 2 || wave == 3) wr(wave);
    __syncthreads();
    if (wave < 2) rd(wave + 2);
    __syncthreads();
    // waves 0/1 hold complementary chunk-partials; exchange one m each and
    // finish in parallel (commutative adds -> bitwise identical to serial).
    if (wave == 1) wr1(0, 0);                      // give wave0 my m=0 partial
    if (wave == 0) wr1(1, 1);                      // give wave1 my m=1 partial
    __syncthreads();
    if (wave == 0) { rd1(0, 0); finalize(0); }
    else if (wave == 1) { rd1(1, 1); finalize(1); }
}

extern "C" void kernel_launch(void* const* d_in, const int* in_sizes, int n_in,
                              void* d_out, int out_size, void* d_ws, size_t ws_size,
                              hipStream_t stream) {
    const float* x  = (const float*)d_in[0];
    const float* Wq = (const float*)d_in[1];
    const float* Wk = (const float*)d_in[2];
    const float* Wv = (const float*)d_in[3];
    float* out = (float*)d_out;

    char* w = (char*)d_ws;
    unsigned short* Wp = (unsigned short*)(w);                            // 384 KB
    unsigned short* Qp = (unsigned short*)(w + (512 << 10));              // 2 MB
    unsigned short* Kp = (unsigned short*)(w + (512 << 10) + (2 << 20));  // 2 MB
    unsigned short* Vp = (unsigned short*)(w + (512 << 10) + (4 << 20));  // 2 MB

    hipLaunchKernelGGL(prep_w, dim3(768), dim3(256), 0, stream, Wq, Wk, Wv, Wp);
    hipLaunchKernelGGL(proj_kernel, dim3(256), dim3(1024), 0, stream, x, Wp, Qp, Kp, Vp);
    hipLaunchKernelGGL(attn_kernel, dim3(512), dim3(512), 0, stream, Qp, Kp, Vp, out);
}